// Round 1
// baseline (784.661 us; speedup 1.0000x reference)
//
#include <hip/hip_runtime.h>
#include <stdint.h>

#define B_SZ 1024
#define F_SZ 104013
#define NFIELD 39
#define N_RAW 312
#define N_PAD 320
#define KB_STEPS 3251            // ceil(104013 / 32)
#define PART_ELEMS ((size_t)B_SZ * N_PAD)

using bf16x8 = __attribute__((ext_vector_type(8))) short;
using f32x4  = __attribute__((ext_vector_type(4))) float;
typedef float f4u __attribute__((vector_size(16), aligned(4)));  // unaligned-tolerant float4

__device__ __forceinline__ unsigned int pack_bf16(float a, float b) {
  // round-half-up to bf16, pack two into one dword (lo = a, hi = b)
  unsigned int ua = __float_as_uint(a) + 0x8000u;
  unsigned int ub = __float_as_uint(b) + 0x8000u;
  return (ua >> 16) | (ub & 0xffff0000u);
}

// ---------------------------------------------------------------------------
// Kernel 1: transpose+convert v (plus w as column 312, zero pad to 320) into
// MFMA B-fragment order: chunk index (kb*20+nt)*64 + lane holds 8 bf16 with
// B[k = kb*32 + (lane>>4)*8 + j][n = nt*16 + (lane&15)], 16B per lane.
// ---------------------------------------------------------------------------
__global__ __launch_bounds__(256) void pack_v(const float* __restrict__ v,
                                              const float* __restrict__ w,
                                              uint4* __restrict__ Bp) {
  const int kb = blockIdx.x;
  const int t  = threadIdx.x;
  __shared__ float vs[32][324];   // 324 stride: 16B-aligned rows + bank skew

  for (int idx = t; idx < 32 * 78; idx += 256) {
    int r = idx / 78, c4 = (idx % 78) * 4;
    int k = kb * 32 + r;
    float4 val = make_float4(0.f, 0.f, 0.f, 0.f);
    if (k < F_SZ) val = *(const float4*)(v + (size_t)k * N_RAW + c4);
    *(float4*)&vs[r][c4] = val;
  }
  if (t < 32) {
    int k = kb * 32 + t;
    vs[t][312] = (k < F_SZ) ? w[k] : 0.f;
#pragma unroll
    for (int c = 313; c < 320; ++c) vs[t][c] = 0.f;
  }
  __syncthreads();

#pragma unroll
  for (int i = 0; i < 5; ++i) {
    int p  = t + 256 * i;          // p = nt*64 + lane
    int l  = p & 63;
    int kr = (l >> 4) * 8;
    int col = (p >> 6) * 16 + (l & 15);
    uint4 o;
    o.x = pack_bf16(vs[kr + 0][col], vs[kr + 1][col]);
    o.y = pack_bf16(vs[kr + 2][col], vs[kr + 3][col]);
    o.z = pack_bf16(vs[kr + 4][col], vs[kr + 5][col]);
    o.w = pack_bf16(vs[kr + 6][col], vs[kr + 7][col]);
    Bp[(size_t)kb * 1280 + p] = o;
  }
}

// ---------------------------------------------------------------------------
// Kernel 2: LDS-free split-K MFMA GEMM.
// Block: 4 waves over 128 rows x 320 cols; wave = 64 rows (4 bands of 16)
// x 160 cols (10 n-tiles of 16). Grid (8 M-tiles, S k-splits).
// A fragments loaded straight from inputs (k-contiguous), cvt fp32->bf16.
// B fragments: one dwordx4 per lane from packed buffer.
// Partials: slab per split s, non-overlapping -> plain stores.
// ---------------------------------------------------------------------------
__global__ __launch_bounds__(256, 1) void gemm_split(const float* __restrict__ A,
                                                     const uint4* __restrict__ Bp,
                                                     float* __restrict__ part) {
  const int S  = gridDim.y;
  const int mt = blockIdx.x, s = blockIdx.y;
  const int t  = threadIdx.x;
  const int w  = t >> 6, l = t & 63;
  const int wr = w >> 1, wc = w & 1;
  const int lm = l & 15, lq = l >> 4;
  const int row0 = mt * 128 + wr * 64;
  const int nt0  = wc * 10;
  const int kb0  = (int)((long long)KB_STEPS * s / S);
  const int kb1  = (int)((long long)KB_STEPS * (s + 1) / S);

  f32x4 acc[4][10];
#pragma unroll
  for (int i = 0; i < 4; ++i)
#pragma unroll
    for (int n = 0; n < 10; ++n) acc[i][n] = (f32x4)0.f;

  const float* ap[4];
#pragma unroll
  for (int i = 0; i < 4; ++i)
    ap[i] = A + (size_t)(row0 + i * 16 + lm) * F_SZ + (size_t)kb0 * 32 + lq * 8;
  const uint4* bp = Bp + ((size_t)kb0 * 20 + nt0) * 64 + l;

  for (int kb = kb0; kb < kb1; ++kb) {
    bf16x8 bfrag[10];
#pragma unroll
    for (int n = 0; n < 10; ++n) {
      uint4 bv = bp[n * 64];
      bfrag[n] = __builtin_bit_cast(bf16x8, bv);
    }
    bf16x8 afrag[4];
    if (kb != KB_STEPS - 1) {
#pragma unroll
      for (int i = 0; i < 4; ++i) {
        f4u v0 = *(const f4u*)(ap[i]);
        f4u v1 = *(const f4u*)(ap[i] + 4);
        uint4 pk = make_uint4(pack_bf16(v0[0], v0[1]), pack_bf16(v0[2], v0[3]),
                              pack_bf16(v1[0], v1[1]), pack_bf16(v1[2], v1[3]));
        afrag[i] = __builtin_bit_cast(bf16x8, pk);
      }
    } else {  // guarded tail: k >= F reads masked to 0 (Bp already zero there)
      int kbase = kb * 32 + lq * 8;
#pragma unroll
      for (int i = 0; i < 4; ++i) {
        float f[8];
#pragma unroll
        for (int j = 0; j < 8; ++j) f[j] = (kbase + j < F_SZ) ? ap[i][j] : 0.f;
        uint4 pk = make_uint4(pack_bf16(f[0], f[1]), pack_bf16(f[2], f[3]),
                              pack_bf16(f[4], f[5]), pack_bf16(f[6], f[7]));
        afrag[i] = __builtin_bit_cast(bf16x8, pk);
      }
    }
#pragma unroll
    for (int i = 0; i < 4; ++i)
#pragma unroll
      for (int n = 0; n < 10; ++n)
        acc[i][n] = __builtin_amdgcn_mfma_f32_16x16x32_bf16(afrag[i], bfrag[n],
                                                            acc[i][n], 0, 0, 0);
#pragma unroll
    for (int i = 0; i < 4; ++i) ap[i] += 32;
    bp += 20 * 64;
  }

  // epilogue: C/D layout col = lane&15, row = (lane>>4)*4 + reg  [m89/m91]
  float* out = part + (size_t)s * PART_ELEMS;
#pragma unroll
  for (int i = 0; i < 4; ++i) {
    int rb = row0 + i * 16 + lq * 4;
#pragma unroll
    for (int n = 0; n < 10; ++n) {
      int col = (nt0 + n) * 16 + lm;
#pragma unroll
      for (int r = 0; r < 4; ++r)
        out[(size_t)(rb + r) * N_PAD + col] = acc[i][n][r];
    }
  }
}

// ---------------------------------------------------------------------------
// Kernel 3: per-row reduction of S partial slabs + FM epilogue.
// out[b] = w0 + C[b][312] + 0.5*(sum_k (sum_f C[b][8f+k])^2 - sum_{n<312} C^2)
// ---------------------------------------------------------------------------
__global__ __launch_bounds__(256) void finalize(const float* __restrict__ part,
                                                const float* __restrict__ w0,
                                                float* __restrict__ out, int S) {
  const int b = blockIdx.x;
  const int t = threadIdx.x;
  __shared__ float crow[N_PAD];
  __shared__ float red[4];
  __shared__ float skl[8];

  for (int n = t; n < N_PAD; n += 256) {
    float acc = 0.f;
    for (int s = 0; s < S; ++s)
      acc += part[(size_t)s * PART_ELEMS + (size_t)b * N_PAD + n];
    crow[n] = acc;
  }
  __syncthreads();

  float sq = 0.f;
  for (int n = t; n < N_RAW; n += 256) sq += crow[n] * crow[n];
#pragma unroll
  for (int off = 32; off; off >>= 1) sq += __shfl_down(sq, off);
  if ((t & 63) == 0) red[t >> 6] = sq;
  if (t < 8) {
    float sk = 0.f;
#pragma unroll
    for (int f = 0; f < NFIELD; ++f) sk += crow[f * 8 + t];
    skl[t] = sk;
  }
  __syncthreads();
  if (t == 0) {
    float sumsq = red[0] + red[1] + red[2] + red[3];
    float ss = 0.f;
#pragma unroll
    for (int k = 0; k < 8; ++k) ss += skl[k] * skl[k];
    out[b] = w0[0] + crow[312] + 0.5f * (ss - sumsq);
  }
}

extern "C" void kernel_launch(void* const* d_in, const int* in_sizes, int n_in,
                              void* d_out, int out_size, void* d_ws, size_t ws_size,
                              hipStream_t stream) {
  const float* inputs = (const float*)d_in[0];
  const float* w0 = (const float*)d_in[1];
  const float* w  = (const float*)d_in[2];
  const float* v  = (const float*)d_in[3];
  float* out = (float*)d_out;

  const size_t PART_BYTES   = PART_ELEMS * sizeof(float);           // 1.31 MB
  const size_t PACKED_BYTES = (size_t)KB_STEPS * 20 * 64 * 16;      // 66.6 MB
  int S = 64;
  while (S > 1 && PACKED_BYTES + (size_t)S * PART_BYTES > ws_size) S >>= 1;

  float* part = (float*)d_ws;
  uint4* Bp   = (uint4*)((char*)d_ws + (size_t)S * PART_BYTES);

  pack_v<<<dim3(KB_STEPS), 256, 0, stream>>>(v, w, Bp);
  gemm_split<<<dim3(8, S), 256, 0, stream>>>(inputs, Bp, part);
  finalize<<<dim3(B_SZ), 256, 0, stream>>>(part, w0, out, S);
}